// Round 1
// baseline (361.994 us; speedup 1.0000x reference)
//
#include <hip/hip_runtime.h>

#define BB 16384
#define DD 4096
#define CC 10
#define MARGIN 0.1f

__global__ void tl_init(double* __restrict__ acc) {
    *acc = 0.0;
}

__global__ __launch_bounds__(256) void tl_main(
        const float* __restrict__ pred,
        const float* __restrict__ anchors,
        const int*   __restrict__ clss,
        const int*   __restrict__ neg_offset,
        double*      __restrict__ acc) {
    const int wave = threadIdx.x >> 6;   // 0..3
    const int lane = threadIdx.x & 63;
    const int row  = blockIdx.x * 4 + wave;   // grid = BB/4, always in range

    const int cls = clss[row];
    const int neg = (cls + 1 + (neg_offset[row] % 9)) % CC;

    const float4* p4 = (const float4*)pred    + (size_t)row * (DD / 4);
    const float4* t4 = (const float4*)anchors + (size_t)cls * (DD / 4);
    const float4* n4 = (const float4*)anchors + (size_t)neg * (DD / 4);

    float s = 0.0f;
    #pragma unroll
    for (int i = 0; i < (DD / 4) / 64; ++i) {   // 16 iterations
        const int j = i * 64 + lane;
        float4 p = p4[j];
        float4 t = t4[j];
        float4 n = n4[j];
        float dp, dn;
        dp = p.x - t.x; dn = p.x - n.x; s += dp * dp - dn * dn;
        dp = p.y - t.y; dn = p.y - n.y; s += dp * dp - dn * dn;
        dp = p.z - t.z; dn = p.z - n.z; s += dp * dp - dn * dn;
        dp = p.w - t.w; dn = p.w - n.w; s += dp * dp - dn * dn;
    }

    // wave-level reduction (64 lanes)
    #pragma unroll
    for (int off = 32; off > 0; off >>= 1)
        s += __shfl_down(s, off, 64);

    __shared__ float wsum[4];
    if (lane == 0) wsum[wave] = s;
    __syncthreads();

    if (threadIdx.x == 0) {
        double tot = (double)wsum[0] + (double)wsum[1]
                   + (double)wsum[2] + (double)wsum[3];
        atomicAdd(acc, tot);   // device-scope by default on CDNA
    }
}

__global__ void tl_finalize(const double* __restrict__ acc,
                            float* __restrict__ out) {
    out[0] = (float)((double)MARGIN + (*acc) / ((double)BB * (double)DD));
}

extern "C" void kernel_launch(void* const* d_in, const int* in_sizes, int n_in,
                              void* d_out, int out_size, void* d_ws, size_t ws_size,
                              hipStream_t stream) {
    const float* pred       = (const float*)d_in[0];
    const float* anchors    = (const float*)d_in[1];
    const int*   clss       = (const int*)d_in[2];
    const int*   neg_offset = (const int*)d_in[3];
    float*  out = (float*)d_out;
    double* acc = (double*)d_ws;

    hipLaunchKernelGGL(tl_init, dim3(1), dim3(1), 0, stream, acc);
    hipLaunchKernelGGL(tl_main, dim3(BB / 4), dim3(256), 0, stream,
                       pred, anchors, clss, neg_offset, acc);
    hipLaunchKernelGGL(tl_finalize, dim3(1), dim3(1), 0, stream, acc, out);
}

// Round 2
// 359.614 us; speedup vs baseline: 1.0066x; 1.0066x over previous
//
#include <hip/hip_runtime.h>

#define BB 16384
#define DD 4096
#define CC 10
#define MARGIN 0.1
#define NBLK (BB / 4)   // 4096 blocks, 4 rows per block (1 row per wave)

__global__ __launch_bounds__(256) void tl_main(
        const float* __restrict__ pred,
        const float* __restrict__ anchors,
        const int*   __restrict__ clss,
        const int*   __restrict__ neg_offset,
        double*      __restrict__ partial) {
    const int wave = threadIdx.x >> 6;   // 0..3
    const int lane = threadIdx.x & 63;
    const int row  = blockIdx.x * 4 + wave;   // grid = BB/4, always in range

    const int cls = clss[row];
    const int neg = (cls + 1 + (neg_offset[row] % 9)) % CC;

    const float4* p4 = (const float4*)pred    + (size_t)row * (DD / 4);
    const float4* t4 = (const float4*)anchors + (size_t)cls * (DD / 4);
    const float4* n4 = (const float4*)anchors + (size_t)neg * (DD / 4);

    float s = 0.0f;
    #pragma unroll
    for (int i = 0; i < (DD / 4) / 64; ++i) {   // 16 iterations
        const int j = i * 64 + lane;
        float4 p = p4[j];
        float4 t = t4[j];
        float4 n = n4[j];
        float dp, dn;
        dp = p.x - t.x; dn = p.x - n.x; s += dp * dp - dn * dn;
        dp = p.y - t.y; dn = p.y - n.y; s += dp * dp - dn * dn;
        dp = p.z - t.z; dn = p.z - n.z; s += dp * dp - dn * dn;
        dp = p.w - t.w; dn = p.w - n.w; s += dp * dp - dn * dn;
    }

    // wave-level reduction (64 lanes)
    #pragma unroll
    for (int off = 32; off > 0; off >>= 1)
        s += __shfl_down(s, off, 64);

    __shared__ float wsum[4];
    if (lane == 0) wsum[wave] = s;
    __syncthreads();

    if (threadIdx.x == 0) {
        partial[blockIdx.x] = (double)wsum[0] + (double)wsum[1]
                            + (double)wsum[2] + (double)wsum[3];
    }
}

__global__ __launch_bounds__(256) void tl_reduce(
        const double* __restrict__ partial,
        float* __restrict__ out) {
    const int tid = threadIdx.x;
    double s = 0.0;
    #pragma unroll
    for (int i = 0; i < NBLK / 256; ++i)   // 16 iterations
        s += partial[i * 256 + tid];

    __shared__ double sh[256];
    sh[tid] = s;
    __syncthreads();
    #pragma unroll
    for (int stride = 128; stride > 0; stride >>= 1) {
        if (tid < stride) sh[tid] += sh[tid + stride];
        __syncthreads();
    }
    if (tid == 0)
        out[0] = (float)(MARGIN + sh[0] / ((double)BB * (double)DD));
}

extern "C" void kernel_launch(void* const* d_in, const int* in_sizes, int n_in,
                              void* d_out, int out_size, void* d_ws, size_t ws_size,
                              hipStream_t stream) {
    const float* pred       = (const float*)d_in[0];
    const float* anchors    = (const float*)d_in[1];
    const int*   clss       = (const int*)d_in[2];
    const int*   neg_offset = (const int*)d_in[3];
    float*  out     = (float*)d_out;
    double* partial = (double*)d_ws;   // 4096 doubles = 32 KB, all written by tl_main

    hipLaunchKernelGGL(tl_main, dim3(NBLK), dim3(256), 0, stream,
                       pred, anchors, clss, neg_offset, partial);
    hipLaunchKernelGGL(tl_reduce, dim3(1), dim3(256), 0, stream, partial, out);
}